// Round 3
// baseline (451.926 us; speedup 1.0000x reference)
//
#include <hip/hip_runtime.h>

typedef unsigned int u32;

#define NB   512   // batches B
#define NJ   101   // target items J
#define NM   50    // context items M
#define NE   128   // embedding E
#define ND   60    // d_alpha D
#define NP   5120  // pad pairs P
#define NT   512   // threads per block
#define DP   61    // cp/tp row stride (floats, odd -> conflict-free column reads)
#define WA   129   // Ac/At/Bc staged row stride (floats, odd -> conflict-free)
#define WRT  130   // R^T staged row stride (floats, even -> aligned float2 reads)
#define ATOFF (ND * WA)          // 7740: At region offset inside w_s
#define EPSV 1e-6f

__global__ __launch_bounds__(NT, 2) void aitv_kernel(
    const int* __restrict__ titems, const int* __restrict__ citems,
    const int* __restrict__ pad_ids,
    const float* __restrict__ t_emb, const float* __restrict__ c_emb,
    const float* __restrict__ Ac_w,  const float* __restrict__ Ac_b,
    const float* __restrict__ At_w,  const float* __restrict__ At_b,
    const float* __restrict__ Bc_w,  const float* __restrict__ Bc_b,
    const float* __restrict__ R_w,   const float* __restrict__ R_b,
    float* __restrict__ out)
{
    const int b    = blockIdx.x;
    const int t    = threadIdx.x;
    const int wid  = t >> 6;
    const int lane = t & 63;

    __shared__ float w_s[16640];        // reused: Ac||At (stride WA) -> Bc (WA) -> R^T (WRT)
    __shared__ float cp_s[NM * DP];
    __shared__ float tp_s[NJ * DP];
    __shared__ float bu_s[NM * NE];
    __shared__ float attn_s[NJ * 52];
    __shared__ float bias_s[2 * ND + 2 * NE];   // Ac_b | At_b | Bc_b | R_b
    __shared__ float nc_s[NM], nt_s[NJ];
    __shared__ int   mask_s[NM], cidx_s[NM], tidx_s[NJ];

    // ---------- P0a: indices, mask zero, biases, stage Ac||At ----------
    if (t < NM) { mask_s[t] = 0; cidx_s[t] = citems[b * NM + t]; }
    if (t < NJ) tidx_s[t] = titems[b * NJ + t];
    if (t < ND) { bias_s[t] = Ac_b[t]; bias_s[ND + t] = At_b[t]; }
    if (t >= 128 && t < 128 + NE) {
        int i = t - 128;
        bias_s[2 * ND + i] = Bc_b[i];
        bias_s[2 * ND + NE + i] = R_b[i];
    }
    for (int i = t; i < ND * NE; i += NT) {      // 7680
        int r = i >> 7, c = i & 127;
        w_s[r * WA + c]         = Ac_w[i];
        w_s[ATOFF + r * WA + c] = At_w[i];
    }
    __syncthreads();

    // ---------- P0b: pad mask; cp = u@Ac^T+b; tp = v@At^T+b ----------
    for (int i = t; i < NP; i += NT)
        if (pad_ids[i] == b) mask_s[pad_ids[NP + i]] = 1;
    for (int i = t; i < NM * ND; i += NT) {
        int m = i / ND, d = i - m * ND;
        const float* ur = c_emb + (size_t)cidx_s[m] * NE;   // wave-broadcast row
        const float* ar = w_s + d * WA;                     // LDS, odd stride
        float acc = bias_s[d];
        #pragma unroll 8
        for (int e = 0; e < NE; e += 4) {
            float4 uv = *(const float4*)(ur + e);
            acc += uv.x * ar[e] + uv.y * ar[e + 1] + uv.z * ar[e + 2] + uv.w * ar[e + 3];
        }
        cp_s[m * DP + d] = acc;
    }
    for (int i = t; i < NJ * ND; i += NT) {
        int j = i / ND, d = i - j * ND;
        const float* vr = t_emb + (size_t)tidx_s[j] * NE;
        const float* ar = w_s + ATOFF + d * WA;
        float acc = bias_s[ND + d];
        #pragma unroll 8
        for (int e = 0; e < NE; e += 4) {
            float4 vv = *(const float4*)(vr + e);
            acc += vv.x * ar[e] + vv.y * ar[e + 1] + vv.z * ar[e + 2] + vv.w * ar[e + 3];
        }
        tp_s[j * DP + d] = acc;
    }
    __syncthreads();

    // ---------- P1: norms (on biased projections, per reference); stage Bc ----------
    if (t < NM) {
        float s = 0.f; const float* r = cp_s + t * DP;
        for (int d = 0; d < ND; d++) s += r[d] * r[d];
        nc_s[t] = fmaxf(sqrtf(s), EPSV);
    } else if (t >= 64 && t < 64 + NJ) {
        float s = 0.f; const float* r = tp_s + (t - 64) * DP;
        for (int d = 0; d < ND; d++) s += r[d] * r[d];
        nt_s[t - 64] = fmaxf(sqrtf(s), EPSV);
    }
    for (int i = t; i < NE * NE; i += NT)        // 16384
        w_s[(i >> 7) * WA + (i & 127)] = Bc_w[i];
    __syncthreads();

    // ---------- P2: bu = u@Bc^T+b; attn = softmax(masked cosine) ----------
    for (int i = t; i < NM * NE; i += NT) {
        int m = i >> 7, e = i & 127;
        const float* ur = c_emb + (size_t)cidx_s[m] * NE;
        const float* br = w_s + e * WA;
        float acc = bias_s[2 * ND + e];
        #pragma unroll 8
        for (int k = 0; k < NE; k += 4) {
            float4 uv = *(const float4*)(ur + k);
            acc += uv.x * br[k] + uv.y * br[k + 1] + uv.z * br[k + 2] + uv.w * br[k + 3];
        }
        bu_s[m * NE + e] = acc;
    }
    for (int j = wid; j < NJ; j += 8) {
        float score = -INFINITY;
        if (lane < NM && mask_s[lane] == 0) {
            float acc = 0.f;
            const float* tpr = tp_s + j * DP;      // broadcast across lanes
            const float* cpr = cp_s + lane * DP;   // odd stride
            #pragma unroll 4
            for (int d = 0; d < ND; d++) acc += tpr[d] * cpr[d];
            score = acc / (nt_s[j] * nc_s[lane]);
        }
        float mx = score;
        for (int o = 32; o; o >>= 1) mx = fmaxf(mx, __shfl_xor(mx, o, 64));
        float p = (mx > -INFINITY) ? __expf(score - mx) : 0.f;   // guard all-masked
        float sm = p;
        for (int o = 32; o; o >>= 1) sm += __shfl_xor(sm, o, 64);
        float inv = (sm > 0.f) ? 1.f / sm : 0.f;
        if (lane < NM) attn_s[j * 52 + lane] = p * inv;
    }
    __syncthreads();

    // ---------- P3: stage R transposed: w_s[k*WRT + e] = R_w[e][k] ----------
    for (int i = t; i < NE * NE; i += NT) {
        int e = i >> 7, k = i & 127;
        w_s[k * WRT + e] = R_w[i];
    }
    __syncthreads();

    // ---------- P4: alpha = attn@bu; out = alpha@R^T + R_b (f32 stores) ----------
    const int e0 = 2 * lane;
    for (int j = wid; j < NJ; j += 8) {
        const float* ar = attn_s + j * 52;
        float a0 = 0.f, a1 = 0.f;
        #pragma unroll 5
        for (int m = 0; m < NM; m++) {
            float am = ar[m];                                   // LDS broadcast
            float2 bv = *(const float2*)(bu_s + m * NE + e0);
            a0 += am * bv.x; a1 += am * bv.y;
        }
        float o0 = bias_s[2 * ND + NE + e0], o1 = bias_s[2 * ND + NE + e0 + 1];
        #pragma unroll 4
        for (int k = 0; k < NE; k += 2) {
            float ak0 = __shfl(a0, k >> 1, 64);                 // alpha[k]
            float ak1 = __shfl(a1, k >> 1, 64);                 // alpha[k+1]
            float2 q0 = *(const float2*)(w_s + k * WRT + e0);       // R[e0][k], R[e0+1][k]
            float2 q1 = *(const float2*)(w_s + (k + 1) * WRT + e0); // R[e0][k+1], R[e0+1][k+1]
            o0 += ak0 * q0.x + ak1 * q1.x;
            o1 += ak0 * q0.y + ak1 * q1.y;
        }
        float2 ov; ov.x = o0; ov.y = o1;
        *(float2*)(out + ((size_t)b * NJ + j) * NE + e0) = ov;
    }
}

extern "C" void kernel_launch(void* const* d_in, const int* in_sizes, int n_in,
                              void* d_out, int out_size, void* d_ws, size_t ws_size,
                              hipStream_t stream) {
    const int*   titems  = (const int*)d_in[0];
    const int*   citems  = (const int*)d_in[1];
    const int*   pad_ids = (const int*)d_in[2];
    const float* t_emb   = (const float*)d_in[3];
    const float* c_emb   = (const float*)d_in[4];
    const float* Ac_w    = (const float*)d_in[5];
    const float* Ac_b    = (const float*)d_in[6];
    const float* At_w    = (const float*)d_in[7];
    const float* At_b    = (const float*)d_in[8];
    const float* Bc_w    = (const float*)d_in[9];
    const float* Bc_b    = (const float*)d_in[10];
    const float* R_w     = (const float*)d_in[11];
    const float* R_b     = (const float*)d_in[12];
    float* out = (float*)d_out;

    aitv_kernel<<<NB, NT, 0, stream>>>(titems, citems, pad_ids, t_emb, c_emb,
                                       Ac_w, Ac_b, At_w, At_b, Bc_w, Bc_b,
                                       R_w, R_b, out);
}

// Round 4
// 380.120 us; speedup vs baseline: 1.1889x; 1.1889x over previous
//
#include <hip/hip_runtime.h>

typedef unsigned short u16;
typedef unsigned int   u32;

#define NB   512   // batches B
#define NJ   101   // target items J
#define NM   50    // context items M
#define NE   128   // embedding E
#define ND   60    // d_alpha D
#define NP   5120  // pad pairs P
#define NT   512   // threads per block
#define DP   61    // cp/tp row stride (floats, odd -> conflict-free column reads)
#define WA   129   // Ac/At f32 stage stride (odd -> conflict-free row reads)
#define EPSV 1e-6f

// ---- LDS arena layout (bytes) ----
// [0      , 36880): cp f32[50*61] @0 ; tp f32[101*61] @12224   (dead after softmax)
//                   overlay: Bc bf16-packed u32[128*65] (33280B), then Rt u32[128*65]
// [36880  , 49680): bu  bf16-packed u32[50*64]                 (written P6)
// [49680  , 69880): attn f32[101*50]                           (written P4)
//                   overlay of [36880,67840): Ac/At f32[60*129] staging (dead after P3)
// [69880  , 72400): bias f32[376] | nc f32[50] | mask/cidx/tidx ints
#define CP_F    0
#define TP_F    3056
#define BU_U32  9220      // 36880/4
#define BU_U16  18440     // 36880/2
#define ATTN_F  12420     // 49680/4
#define ACAT_F  9220      // 36880/4
#define BIAS_F  17470     // 69880/4
#define NC_F    17846
#define MASK_I  17896
#define CIDX_I  17946
#define TIDX_I  17996
#define ARENA_BYTES 72400

__device__ __forceinline__ u16 f2b(float f) {
    union { float f; u32 i; } x; x.f = f;
    u32 r = x.i + 0x7FFFu + ((x.i >> 16) & 1u);   // RTNE
    return (u16)(r >> 16);
}
__device__ __forceinline__ float lo16f(u32 w) {
    union { u32 i; float f; } x; x.i = w << 16; return x.f;
}
__device__ __forceinline__ float hi16f(u32 w) {
    union { u32 i; float f; } x; x.i = w & 0xFFFF0000u; return x.f;
}
__device__ __forceinline__ u32 pack2(float a, float b) {
    return (u32)f2b(a) | ((u32)f2b(b) << 16);
}

__global__ __launch_bounds__(NT, 4) void aitv_kernel(
    const int* __restrict__ titems, const int* __restrict__ citems,
    const int* __restrict__ pad_ids,
    const float* __restrict__ t_emb, const float* __restrict__ c_emb,
    const float* __restrict__ Ac_w,  const float* __restrict__ Ac_b,
    const float* __restrict__ At_w,  const float* __restrict__ At_b,
    const float* __restrict__ Bc_w,  const float* __restrict__ Bc_b,
    const float* __restrict__ R_w,   const float* __restrict__ R_b,
    float* __restrict__ out)
{
    const int b    = blockIdx.x;
    const int t    = threadIdx.x;
    const int wid  = t >> 6;
    const int lane = t & 63;

    __shared__ __align__(16) char arena[ARENA_BYTES];
    float* af = (float*)arena;
    u32*   au = (u32*)arena;
    u16*   ah = (u16*)arena;
    int*   ai = (int*)arena;

    float* cp   = af + CP_F;     // [50][DP]
    float* tp   = af + TP_F;     // [101][DP]
    float* acat = af + ACAT_F;   // [60][WA] f32 weight stage (Ac, then At)
    u32*   buP  = au + BU_U32;   // [50][64] packed bf16 pairs
    u16*   buH  = ah + BU_U16;
    float* attn = af + ATTN_F;   // [101][50]
    float* bias = af + BIAS_F;   // Ac_b | At_b | Bc_b | R_b
    float* ncv  = af + NC_F;
    int*   mskv = ai + MASK_I;
    int*   cidx = ai + CIDX_I;
    int*   tidx = ai + TIDX_I;

    // ---- P0: indices, biases, mask zero, stage Ac (f32) ----
    if (t < NM) { mskv[t] = 0; cidx[t] = citems[b * NM + t]; }
    if (t < NJ) tidx[t] = titems[b * NJ + t];
    if (t < ND) { bias[t] = Ac_b[t]; bias[ND + t] = At_b[t]; }
    if (t >= 128 && t < 256) {
        int i = t - 128;
        bias[2 * ND + i] = Bc_b[i];
        bias[2 * ND + NE + i] = R_b[i];
    }
    for (int i = t; i < ND * NE; i += NT)
        acat[(i >> 7) * WA + (i & 127)] = Ac_w[i];
    __syncthreads();

    // ---- P1: pad-mask scan; cp = u@Ac^T + b ----
    for (int i = t; i < NP; i += NT)
        if (pad_ids[i] == b) mskv[pad_ids[NP + i]] = 1;
    for (int i = t; i < NM * ND; i += NT) {
        int m = i / ND, d = i - m * ND;
        const float* ur = c_emb + (size_t)cidx[m] * NE;   // wave-broadcast row
        const float* ar = acat + d * WA;                  // conflict-free (odd stride)
        float acc = bias[d];
        #pragma unroll 8
        for (int e = 0; e < NE; e += 4) {
            float4 uv = *(const float4*)(ur + e);
            acc += uv.x * ar[e] + uv.y * ar[e + 1] + uv.z * ar[e + 2] + uv.w * ar[e + 3];
        }
        cp[m * DP + d] = acc;
    }
    __syncthreads();

    // ---- P2: stage At (f32, same region); nc norms ----
    for (int i = t; i < ND * NE; i += NT)
        acat[(i >> 7) * WA + (i & 127)] = At_w[i];
    if (t < NM) {
        float s = 0.f; const float* r = cp + t * DP;
        for (int d = 0; d < ND; d++) s += r[d] * r[d];
        ncv[t] = fmaxf(sqrtf(s), EPSV);
    }
    __syncthreads();

    // ---- P3: tp = v@At^T + b ----
    for (int i = t; i < NJ * ND; i += NT) {
        int j = i / ND, d = i - j * ND;
        const float* vr = t_emb + (size_t)tidx[j] * NE;
        const float* ar = acat + d * WA;
        float acc = bias[ND + d];
        #pragma unroll 8
        for (int e = 0; e < NE; e += 4) {
            float4 vv = *(const float4*)(vr + e);
            acc += vv.x * ar[e] + vv.y * ar[e + 1] + vv.z * ar[e + 2] + vv.w * ar[e + 3];
        }
        tp[j * DP + d] = acc;
    }
    __syncthreads();

    // ---- P4: softmax(masked cosine) -> attn ; nt inline per wave ----
    for (int j = wid; j < NJ; j += 8) {
        const float* tpr = tp + j * DP;
        float q = (lane < ND) ? tpr[lane] * tpr[lane] : 0.f;
        for (int o = 32; o; o >>= 1) q += __shfl_xor(q, o, 64);
        float ntj = fmaxf(sqrtf(q), EPSV);
        float score = -INFINITY;
        if (lane < NM && mskv[lane] == 0) {
            float acc = 0.f;
            const float* cpr = cp + lane * DP;   // stride 61: conflict-free columns
            #pragma unroll 4
            for (int d = 0; d < ND; d++) acc += tpr[d] * cpr[d];
            score = acc / (ntj * ncv[lane]);
        }
        float mx = score;
        for (int o = 32; o; o >>= 1) mx = fmaxf(mx, __shfl_xor(mx, o, 64));
        float p = (mx > -INFINITY) ? __expf(score - mx) : 0.f;
        float sm = p;
        for (int o = 32; o; o >>= 1) sm += __shfl_xor(sm, o, 64);
        float inv = (sm > 0.f) ? 1.f / sm : 0.f;
        if (lane < NM) attn[j * NM + lane] = p * inv;
    }
    __syncthreads();

    // ---- P5: stage Bc bf16-packed into cp/tp region: au[e*65+k2] = {Bc[e][2k2],Bc[e][2k2+1]} ----
    for (int i = t; i < NE * 64; i += NT) {
        int e = i >> 6, k2 = i & 63;
        float2 v = *(const float2*)(Bc_w + e * NE + 2 * k2);   // coalesced
        au[e * 65 + k2] = pack2(v.x, v.y);                     // bank (e+k2)%32: free
    }
    __syncthreads();

    // ---- P6: bu = u@Bc^T + b -> bf16-packed ----
    for (int i = t; i < NM * NE; i += NT) {
        int m = i >> 7, e = i & 127;
        const float* ur = c_emb + (size_t)cidx[m] * NE;   // broadcast
        const u32* br = au + e * 65;                      // bank (e+k2)%32: free
        float acc = bias[2 * ND + e];
        #pragma unroll 8
        for (int k2 = 0; k2 < 64; k2++) {
            u32 w = br[k2];
            float2 uv = *(const float2*)(ur + 2 * k2);
            acc += uv.x * lo16f(w) + uv.y * hi16f(w);
        }
        buH[m * NE + e] = f2b(acc);
    }
    __syncthreads();

    // ---- P7: stage R^T bf16-packed: au[k*65+e2] = {R[2e2][k], R[2e2+1][k]} ----
    for (int i = t; i < 64 * NE; i += NT) {
        int k = i & 127, e2 = i >> 7;
        float x0 = R_w[(2 * e2) * NE + k];       // coalesced within row
        float x1 = R_w[(2 * e2 + 1) * NE + k];
        au[k * 65 + e2] = pack2(x0, x1);         // bank (k+e2)%32: free
    }
    __syncthreads();

    // ---- P8: alpha = attn@bu ; out = alpha@R^T + R_b ----
    const int e0 = 2 * lane;
    for (int j = wid; j < NJ; j += 8) {
        const float* ar = attn + j * NM;
        float a0 = 0.f, a1 = 0.f;   // alpha[j][e0], alpha[j][e0+1]
        #pragma unroll 5
        for (int m = 0; m < NM; m++) {
            float am = ar[m];                  // broadcast
            u32 w = buP[m * 64 + lane];        // bank lane%32: 2-way free
            a0 += am * lo16f(w); a1 += am * hi16f(w);
        }
        float o0 = bias[2 * ND + NE + e0], o1 = bias[2 * ND + NE + e0 + 1];
        #pragma unroll 4
        for (int k2 = 0; k2 < 64; k2++) {
            float ak0 = __shfl(a0, k2, 64);    // alpha[2k2]  (readlane: k2 uniform)
            float ak1 = __shfl(a1, k2, 64);    // alpha[2k2+1]
            u32 w0 = au[(2 * k2) * 65 + lane];      // R[e0][2k2],   R[e0+1][2k2]
            u32 w1 = au[(2 * k2 + 1) * 65 + lane];  // R[e0][2k2+1], R[e0+1][2k2+1]
            o0 += ak0 * lo16f(w0) + ak1 * lo16f(w1);
            o1 += ak0 * hi16f(w0) + ak1 * hi16f(w1);
        }
        float2 ov; ov.x = o0; ov.y = o1;
        *(float2*)(out + ((size_t)b * NJ + j) * NE + e0) = ov;
    }
}

extern "C" void kernel_launch(void* const* d_in, const int* in_sizes, int n_in,
                              void* d_out, int out_size, void* d_ws, size_t ws_size,
                              hipStream_t stream) {
    const int*   titems  = (const int*)d_in[0];
    const int*   citems  = (const int*)d_in[1];
    const int*   pad_ids = (const int*)d_in[2];
    const float* t_emb   = (const float*)d_in[3];
    const float* c_emb   = (const float*)d_in[4];
    const float* Ac_w    = (const float*)d_in[5];
    const float* Ac_b    = (const float*)d_in[6];
    const float* At_w    = (const float*)d_in[7];
    const float* At_b    = (const float*)d_in[8];
    const float* Bc_w    = (const float*)d_in[9];
    const float* Bc_b    = (const float*)d_in[10];
    const float* R_w     = (const float*)d_in[11];
    const float* R_b     = (const float*)d_in[12];
    float* out = (float*)d_out;

    aitv_kernel<<<NB, NT, 0, stream>>>(titems, citems, pad_ids, t_emb, c_emb,
                                       Ac_w, Ac_b, At_w, At_b, Bc_w, Bc_b,
                                       R_w, R_b, out);
}

// Round 5
// 219.550 us; speedup vs baseline: 2.0584x; 1.7314x over previous
//
#include <hip/hip_runtime.h>

typedef unsigned short u16;
typedef unsigned int   u32;
typedef short bf8 __attribute__((ext_vector_type(8)));   // 8 bf16 payloads (4 VGPRs)
typedef float f4  __attribute__((ext_vector_type(4)));   // MFMA accumulator

#define NB   512
#define NJ   101
#define NM   50
#define NE   128
#define ND   60
#define NP   5120
#define NT   512
#define EPSV 1e-6f

// ---- LDS arena (byte offsets). Overlays:
//  A: v bf16[112][136] -> scores f32[112][68] -> alpha bf16[112][136]  (all 30464B)
#define VS_B    0
#define US_B    30464     // u  bf16 [64][136]   17408B
#define WS_B    47872     // w  bf16 [128][136]  34816B : At(0..63)|Ac(64..127) -> Bc -> R
#define TP_B    82688     // tp/attn bf16 [112][72] 16128B (overlay)
#define CP_B    98816     // cp bf16 [64][72]     9216B
#define BUT_B   108032    // buT bf16 [128][72]  18432B  (bu transposed: [e][m])
#define NT_B    126464    // f32[112]
#define NC_B    126912    // f32[64]
#define BAT_B   127168    // f32[64]  At_b (zero-padded)
#define BAC_B   127424    // f32[64]  Ac_b
#define BCB_B   127680    // f32[128] Bc_b
#define RB_B    128192    // f32[128] R_b
#define MSK_B   128704    // int[64]
#define ARENA_B 128960

__device__ __forceinline__ u16 f2b(float f) {
    union { float f; u32 i; } x; x.f = f;
    u32 r = x.i + 0x7FFFu + ((x.i >> 16) & 1u);   // RTNE
    return (u16)(r >> 16);
}
__device__ __forceinline__ float lo16f(u32 w) {
    union { u32 i; float f; } x; x.i = w << 16; return x.f;
}
__device__ __forceinline__ float hi16f(u32 w) {
    union { u32 i; float f; } x; x.i = w & 0xFFFF0000u; return x.f;
}
__device__ __forceinline__ u32 pack2(float a, float b) {
    return (u32)f2b(a) | ((u32)f2b(b) << 16);
}
__device__ __forceinline__ bf8 ldfrag(const u16* p) { return *(const bf8*)p; }

__global__ __launch_bounds__(NT, 2) void aitv_kernel(
    const int* __restrict__ titems, const int* __restrict__ citems,
    const int* __restrict__ pad_ids,
    const float* __restrict__ t_emb, const float* __restrict__ c_emb,
    const float* __restrict__ Ac_w,  const float* __restrict__ Ac_b,
    const float* __restrict__ At_w,  const float* __restrict__ At_b,
    const float* __restrict__ Bc_w,  const float* __restrict__ Bc_b,
    const float* __restrict__ R_w,   const float* __restrict__ R_b,
    float* __restrict__ out)
{
    const int b    = blockIdx.x;
    const int t    = threadIdx.x;
    const int wid  = t >> 6;
    const int lane = t & 63;
    const int l15  = lane & 15;
    const int quad = lane >> 4;

    __shared__ __align__(16) char arena[ARENA_B];
    u16*   vs16   = (u16*)(arena + VS_B);    u32* vs32 = (u32*)(arena + VS_B);
    float* scoresF= (float*)(arena + VS_B);
    u16*   alpha16= (u16*)(arena + VS_B);
    u16*   us16   = (u16*)(arena + US_B);    u32* us32 = (u32*)(arena + US_B);
    u16*   ws16   = (u16*)(arena + WS_B);    u32* ws32 = (u32*)(arena + WS_B);
    u16*   tp16   = (u16*)(arena + TP_B);    u32* tpu32= (u32*)(arena + TP_B);
    u16*   attn16 = (u16*)(arena + TP_B);
    u16*   cp16   = (u16*)(arena + CP_B);    u32* cpu32= (u32*)(arena + CP_B);
    u16*   but16  = (u16*)(arena + BUT_B);
    float* ntf    = (float*)(arena + NT_B);
    float* ncf    = (float*)(arena + NC_B);
    float* bat    = (float*)(arena + BAT_B);
    float* bac    = (float*)(arena + BAC_B);
    float* bcb    = (float*)(arena + BCB_B);
    float* rbf    = (float*)(arena + RB_B);
    int*   msk    = (int*)(arena + MSK_B);

    // ================= P0: stage v, u, At|Ac (bf16, zero-padded), biases, mask=0 ======
    for (int i = t; i < 112 * 64; i += NT) {           // v: [112][136] rows 101..111 = 0
        int row = i >> 6, c2 = i & 63;
        u32 val = 0;
        if (row < NJ) {
            int idx = titems[b * NJ + row];            // wave-uniform
            float2 x = *(const float2*)(t_emb + (size_t)idx * NE + 2 * c2);
            val = pack2(x.x, x.y);
        }
        vs32[row * 68 + c2] = val;
    }
    for (int i = t; i < 64 * 64; i += NT) {            // u: rows 50..63 = 0
        int row = i >> 6, c2 = i & 63;
        u32 val = 0;
        if (row < NM) {
            int idx = citems[b * NM + row];
            float2 x = *(const float2*)(c_emb + (size_t)idx * NE + 2 * c2);
            val = pack2(x.x, x.y);
        }
        us32[row * 68 + c2] = val;
    }
    for (int i = t; i < 128 * 64; i += NT) {           // At rows 0..59 | Ac rows 64..123, pads 0
        int row = i >> 6, c2 = i & 63;
        u32 val = 0;
        if (row < ND) {
            float2 x = *(const float2*)(At_w + row * NE + 2 * c2);
            val = pack2(x.x, x.y);
        } else if (row >= 64 && row < 64 + ND) {
            float2 x = *(const float2*)(Ac_w + (row - 64) * NE + 2 * c2);
            val = pack2(x.x, x.y);
        }
        ws32[row * 68 + c2] = val;
    }
    if (t < 64) {
        bat[t] = (t < ND) ? At_b[t] : 0.f;
        bac[t] = (t < ND) ? Ac_b[t] : 0.f;
        msk[t] = 0;
    } else if (t >= 64 && t < 192) {
        int i = t - 64;
        bcb[i] = Bc_b[i];
        rbf[i] = R_b[i];
    }
    __syncthreads();

    // ================= P1: pad-mask scan; MFMA tp (v@At^T+b), cp (u@Ac^T+b) ==========
    for (int i = t; i < NP; i += NT)
        if (pad_ids[i] == b) msk[pad_ids[NP + i]] = 1;

    for (int u = wid; u < 44; u += 8) {
        if (u < 28) {                                   // tp: jt 0..6 x dt 0..3, K=128
            int jt = u >> 2, dt = u & 3;
            float bv = bat[dt * 16 + l15];
            f4 acc = {bv, bv, bv, bv};
            for (int ks = 0; ks < 4; ks++) {
                bf8 a  = ldfrag(vs16 + (jt * 16 + l15) * 136 + ks * 32 + quad * 8);
                bf8 bb = ldfrag(ws16 + (dt * 16 + l15) * 136 + ks * 32 + quad * 8);
                acc = __builtin_amdgcn_mfma_f32_16x16x32_bf16(a, bb, acc, 0, 0, 0);
            }
            int d = dt * 16 + l15, j0 = jt * 16 + quad * 4;
            for (int r = 0; r < 4; r++) tp16[(j0 + r) * 72 + d] = f2b(acc[r]);
        } else {                                        // cp: mt 0..3 x dt 0..3
            int uu = u - 28, mt = uu >> 2, dt = uu & 3;
            float bv = bac[dt * 16 + l15];
            f4 acc = {bv, bv, bv, bv};
            for (int ks = 0; ks < 4; ks++) {
                bf8 a  = ldfrag(us16 + (mt * 16 + l15) * 136 + ks * 32 + quad * 8);
                bf8 bb = ldfrag(ws16 + (64 + dt * 16 + l15) * 136 + ks * 32 + quad * 8);
                acc = __builtin_amdgcn_mfma_f32_16x16x32_bf16(a, bb, acc, 0, 0, 0);
            }
            int d = dt * 16 + l15, m0 = mt * 16 + quad * 4;
            for (int r = 0; r < 4; r++) cp16[(m0 + r) * 72 + d] = f2b(acc[r]);
        }
    }
    __syncthreads();

    // ================= P2: MFMA scores (tp@cp^T) -> f32; stage Bc; norms =============
    for (int u = wid; u < 28; u += 8) {                 // jt 0..6 x mt 0..3, K=64
        int jt = u >> 2, mt = u & 3;
        f4 acc = {0.f, 0.f, 0.f, 0.f};
        for (int ks = 0; ks < 2; ks++) {
            bf8 a  = ldfrag(tp16 + (jt * 16 + l15) * 72 + ks * 32 + quad * 8);
            bf8 bb = ldfrag(cp16 + (mt * 16 + l15) * 72 + ks * 32 + quad * 8);
            acc = __builtin_amdgcn_mfma_f32_16x16x32_bf16(a, bb, acc, 0, 0, 0);
        }
        int m = mt * 16 + l15, j0 = jt * 16 + quad * 4;
        for (int r = 0; r < 4; r++) scoresF[(j0 + r) * 68 + m] = acc[r];
    }
    for (int i = t; i < 128 * 64; i += NT) {            // stage Bc (At/Ac dead)
        int row = i >> 6, c2 = i & 63;
        float2 x = *(const float2*)(Bc_w + row * NE + 2 * c2);
        ws32[row * 68 + c2] = pack2(x.x, x.y);
    }
    if (t < 176) {                                      // norms from bf16 tp/cp (f32 sum)
        int r = (t < 112) ? t : (t - 112);
        const u32* src = (t < 112) ? tpu32 : cpu32;
        float s = 0.f;
        for (int c2 = 0; c2 < 32; c2++) {
            u32 w = src[r * 36 + c2];
            float x = lo16f(w), y = hi16f(w);
            s += x * x + y * y;
        }
        float nv = fmaxf(sqrtf(s), EPSV);
        if (t < 112) ntf[r] = nv; else ncf[r] = nv;
    }
    __syncthreads();

    // ================= P3: softmax -> attn bf16; MFMA bu -> buT bf16 =================
    for (int u = wid; u < 32; u += 8) {                 // bu: mt 0..3 x et 0..7, K=128
        int mt = u >> 3, et = u & 7;
        float bv = bcb[et * 16 + l15];
        f4 acc = {bv, bv, bv, bv};
        for (int ks = 0; ks < 4; ks++) {
            bf8 a  = ldfrag(us16 + (mt * 16 + l15) * 136 + ks * 32 + quad * 8);
            bf8 bb = ldfrag(ws16 + (et * 16 + l15) * 136 + ks * 32 + quad * 8);
            acc = __builtin_amdgcn_mfma_f32_16x16x32_bf16(a, bb, acc, 0, 0, 0);
        }
        int e = et * 16 + l15, m0 = mt * 16 + quad * 4;  // transposed store: buT[e][m]
        *(u32*)(but16 + e * 72 + m0)     = pack2(acc[0], acc[1]);
        *(u32*)(but16 + e * 72 + m0 + 2) = pack2(acc[2], acc[3]);
    }
    for (int j = wid; j < 112; j += 8) {
        float sc = -INFINITY;
        if (lane < NM && msk[lane] == 0)
            sc = scoresF[j * 68 + lane] / (ntf[j] * ncf[lane]);
        float mx = sc;
        for (int o = 32; o; o >>= 1) mx = fmaxf(mx, __shfl_xor(mx, o, 64));
        float p = (mx > -INFINITY) ? __expf(sc - mx) : 0.f;
        float sm = p;
        for (int o = 32; o; o >>= 1) sm += __shfl_xor(sm, o, 64);
        float inv = (sm > 0.f) ? 1.f / sm : 0.f;
        attn16[j * 72 + lane] = (lane < NM) ? f2b(p * inv) : (u16)0;
    }
    __syncthreads();

    // ================= P4: MFMA alpha (attn@bu) -> bf16; stage R =====================
    for (int u = wid; u < 56; u += 8) {                 // jt 0..6 x et 0..7, K=64
        int jt = u >> 3, et = u & 7;
        f4 acc = {0.f, 0.f, 0.f, 0.f};
        for (int ks = 0; ks < 2; ks++) {
            bf8 a  = ldfrag(attn16 + (jt * 16 + l15) * 72 + ks * 32 + quad * 8);
            bf8 bb = ldfrag(but16  + (et * 16 + l15) * 72 + ks * 32 + quad * 8);
            acc = __builtin_amdgcn_mfma_f32_16x16x32_bf16(a, bb, acc, 0, 0, 0);
        }
        int e = et * 16 + l15, j0 = jt * 16 + quad * 4;
        for (int r = 0; r < 4; r++) alpha16[(j0 + r) * 136 + e] = f2b(acc[r]);
    }
    for (int i = t; i < 128 * 64; i += NT) {            // stage R (Bc dead)
        int row = i >> 6, c2 = i & 63;
        float2 x = *(const float2*)(R_w + row * NE + 2 * c2);
        ws32[row * 68 + c2] = pack2(x.x, x.y);
    }
    __syncthreads();

    // ================= P5: MFMA out (alpha@R^T + R_b) -> global f32 ==================
    for (int u = wid; u < 56; u += 8) {                 // jt 0..6 x et 0..7, K=128
        int jt = u >> 3, et = u & 7;
        float bv = rbf[et * 16 + l15];
        f4 acc = {bv, bv, bv, bv};
        for (int ks = 0; ks < 4; ks++) {
            bf8 a  = ldfrag(alpha16 + (jt * 16 + l15) * 136 + ks * 32 + quad * 8);
            bf8 bb = ldfrag(ws16    + (et * 16 + l15) * 136 + ks * 32 + quad * 8);
            acc = __builtin_amdgcn_mfma_f32_16x16x32_bf16(a, bb, acc, 0, 0, 0);
        }
        int e = et * 16 + l15, j0 = jt * 16 + quad * 4;
        for (int r = 0; r < 4; r++) {
            int j = j0 + r;
            if (j < NJ) out[((size_t)b * NJ + j) * NE + e] = acc[r];
        }
    }
}

extern "C" void kernel_launch(void* const* d_in, const int* in_sizes, int n_in,
                              void* d_out, int out_size, void* d_ws, size_t ws_size,
                              hipStream_t stream) {
    const int*   titems  = (const int*)d_in[0];
    const int*   citems  = (const int*)d_in[1];
    const int*   pad_ids = (const int*)d_in[2];
    const float* t_emb   = (const float*)d_in[3];
    const float* c_emb   = (const float*)d_in[4];
    const float* Ac_w    = (const float*)d_in[5];
    const float* Ac_b    = (const float*)d_in[6];
    const float* At_w    = (const float*)d_in[7];
    const float* At_b    = (const float*)d_in[8];
    const float* Bc_w    = (const float*)d_in[9];
    const float* Bc_b    = (const float*)d_in[10];
    const float* R_w     = (const float*)d_in[11];
    const float* R_b     = (const float*)d_in[12];
    float* out = (float*)d_out;

    aitv_kernel<<<NB, NT, 0, stream>>>(titems, citems, pad_ids, t_emb, c_emb,
                                       Ac_w, Ac_b, At_w, At_b, Bc_w, Bc_b,
                                       R_w, R_b, out);
}

// Round 6
// 203.787 us; speedup vs baseline: 2.2176x; 1.0774x over previous
//
#include <hip/hip_runtime.h>

typedef unsigned short u16;
typedef unsigned int   u32;
typedef short bf8 __attribute__((ext_vector_type(8)));   // 8 bf16 payloads (4 VGPRs)
typedef float f4  __attribute__((ext_vector_type(4)));   // MFMA accumulator

#define NB   512
#define NJ   101
#define NM   50
#define NE   128
#define ND   60
#define NP   5120
#define NT   512
#define EPSV 1e-6f

// ---- LDS arena (byte offsets) ----
// X: u bf16 [64][136]                         (live P0-P3)
// W: At|Ac bf16 [128][136]  (P0-P1)
//    -> scores f32 [112][68] (P2)             (same bytes)
//    -> bu bf16 [64][136] @ +0  (P3-P4)
//       gT bf16 [128][68] @ +17408 (P4-P5)
// T: tp bf16 [112][72] (P1-P2a) -> attn (P2b-P5)
// C: cp bf16 [64][72] (P1-P2a)
#define X_B    0
#define W_B    17408
#define GT_B   34816     // W_B + 17408
#define T_B    52224
#define C_B    68352
#define NTF_B  77568     // f32[112]
#define NCF_B  78016     // f32[64]
#define BAT_B  78272     // f32[64]
#define BAC_B  78528     // f32[64]
#define BCB_B  78784     // f32[128]
#define RB_B   79296     // f32[128]
#define MSK_B  79808     // int[64]
#define TIDX_B 80064     // int[112] (padded with row 100)
#define ARENA  80512

__device__ __forceinline__ u32 pk2(float a, float b) {    // pack 2xbf16, round-half-up
    u32 ia = __float_as_uint(a) + 0x8000u;
    u32 ib = __float_as_uint(b) + 0x8000u;
    return (ia >> 16) | (ib & 0xFFFF0000u);
}
__device__ __forceinline__ u16 f2bh(float f) {
    return (u16)((__float_as_uint(f) + 0x8000u) >> 16);
}
__device__ __forceinline__ bf8 gfrag(const float* p) {    // 8 f32 (global) -> bf16 frag
    const float4* q = (const float4*)p;
    float4 x = q[0], y = q[1];
    union { u32 u[4]; bf8 v; } r;
    r.u[0] = pk2(x.x, x.y); r.u[1] = pk2(x.z, x.w);
    r.u[2] = pk2(y.x, y.y); r.u[3] = pk2(y.z, y.w);
    return r.v;
}

__global__ __launch_bounds__(NT, 4) void aitv_kernel(
    const int* __restrict__ titems, const int* __restrict__ citems,
    const int* __restrict__ pad_ids,
    const float* __restrict__ t_emb, const float* __restrict__ c_emb,
    const float* __restrict__ Ac_w,  const float* __restrict__ Ac_b,
    const float* __restrict__ At_w,  const float* __restrict__ At_b,
    const float* __restrict__ Bc_w,  const float* __restrict__ Bc_b,
    const float* __restrict__ R_w,   const float* __restrict__ R_b,
    float* __restrict__ out)
{
    const int b    = blockIdx.x;
    const int t    = threadIdx.x;
    const int wid  = t >> 6;
    const int lane = t & 63;
    const int l15  = lane & 15;
    const int quad = lane >> 4;

    __shared__ __align__(16) char arena[ARENA];
    u16*   us16 = (u16*)(arena + X_B);   u32* us32 = (u32*)(arena + X_B);
    u16*   ws16 = (u16*)(arena + W_B);   u32* ws32 = (u32*)(arena + W_B);
    float* Wf   = (float*)(arena + W_B);                 // scores overlay
    u16*   buW  = (u16*)(arena + W_B);                   // bu overlay [64][136]
    u16*   gT16 = (u16*)(arena + GT_B);                  // gT [128][68]
    u16*   tp16 = (u16*)(arena + T_B);   u32* tpu32 = (u32*)(arena + T_B);
    u16*   at16 = (u16*)(arena + T_B);                   // attn overlay
    u16*   cp16 = (u16*)(arena + C_B);   u32* cpu32 = (u32*)(arena + C_B);
    float* ntf  = (float*)(arena + NTF_B);
    float* ncf  = (float*)(arena + NCF_B);
    float* bat  = (float*)(arena + BAT_B);
    float* bac  = (float*)(arena + BAC_B);
    float* bcb  = (float*)(arena + BCB_B);
    float* rb   = (float*)(arena + RB_B);
    int*   msk  = (int*)(arena + MSK_B);
    int*   tidx = (int*)(arena + TIDX_B);

    // ===== P0: stage u (bf16, zero-padded rows 50..63), At|Ac, biases, idx, mask =====
    for (int i = t; i < 64 * 64; i += NT) {
        int row = i >> 6, c2 = i & 63;            // row wave-uniform, c2 = lane
        u32 val = 0;
        if (row < NM) {
            int idx = citems[b * NM + row];       // wave-uniform scalar load
            float2 x = *(const float2*)(c_emb + (size_t)idx * NE + 2 * c2);
            val = pk2(x.x, x.y);
        }
        us32[row * 68 + c2] = val;
    }
    for (int i = t; i < 128 * 64; i += NT) {      // At rows 0..59 | Ac rows 64..123
        int row = i >> 6, c2 = i & 63;
        u32 val = 0;
        if (row < ND) {
            float2 x = *(const float2*)(At_w + row * NE + 2 * c2);
            val = pk2(x.x, x.y);
        } else if (row >= 64 && row < 64 + ND) {
            float2 x = *(const float2*)(Ac_w + (row - 64) * NE + 2 * c2);
            val = pk2(x.x, x.y);
        }
        ws32[row * 68 + c2] = val;
    }
    if (t < 64) {
        msk[t] = 0;
        bat[t] = (t < ND) ? At_b[t] : 0.f;
        bac[t] = (t < ND) ? Ac_b[t] : 0.f;
    } else if (t >= 128 && t < 256) {
        int i = t - 128;
        bcb[i] = Bc_b[i];
        rb[i]  = R_b[i];
    } else if (t >= 256 && t < 368) {
        int i = t - 256;
        tidx[i] = titems[b * NJ + ((i < NJ) ? i : (NJ - 1))];
    }
    __syncthreads();

    // ===== P1: pad-mask scan; tp = v(global)@At^T + b -> T; cp = u@Ac^T + b -> C ====
    for (int i = t; i < NP; i += NT)
        if (pad_ids[i] == b) msk[pad_ids[NP + i]] = 1;

    for (int u = wid; u < 44; u += 8) {
        if (u < 28) {                              // tp: jt 0..6 x dt 0..3, K=128
            int jt = u >> 2, dt = u & 3;
            const float* vrow = t_emb + (size_t)tidx[jt * 16 + l15] * NE;
            float bv = bat[dt * 16 + l15];
            f4 acc = {bv, bv, bv, bv};
            #pragma unroll
            for (int ks = 0; ks < 4; ks++) {
                bf8 a  = gfrag(vrow + ks * 32 + quad * 8);
                bf8 bb = *(const bf8*)(ws16 + (dt * 16 + l15) * 136 + ks * 32 + quad * 8);
                acc = __builtin_amdgcn_mfma_f32_16x16x32_bf16(a, bb, acc, 0, 0, 0);
            }
            int d = dt * 16 + l15, j0 = jt * 16 + quad * 4;
            for (int r = 0; r < 4; r++) tp16[(j0 + r) * 72 + d] = f2bh(acc[r]);
        } else {                                   // cp: mt 0..3 x dt 0..3, K=128
            int uu = u - 28, mt = uu >> 2, dt = uu & 3;
            float bv = bac[dt * 16 + l15];
            f4 acc = {bv, bv, bv, bv};
            #pragma unroll
            for (int ks = 0; ks < 4; ks++) {
                bf8 a  = *(const bf8*)(us16 + (mt * 16 + l15) * 136 + ks * 32 + quad * 8);
                bf8 bb = *(const bf8*)(ws16 + (64 + dt * 16 + l15) * 136 + ks * 32 + quad * 8);
                acc = __builtin_amdgcn_mfma_f32_16x16x32_bf16(a, bb, acc, 0, 0, 0);
            }
            int d = dt * 16 + l15, m0 = mt * 16 + quad * 4;
            for (int r = 0; r < 4; r++) cp16[(m0 + r) * 72 + d] = f2bh(acc[r]);
        }
    }
    __syncthreads();

    // ===== P2a: norms; scores = tp@cp^T -> W (f32) =====
    if (t < 112) {
        float s = 0.f;
        for (int c2 = 0; c2 < 32; c2++) {
            u32 w = tpu32[t * 36 + c2];
            union { u32 i; float f; } x, y; x.i = w << 16; y.i = w & 0xFFFF0000u;
            s += x.f * x.f + y.f * y.f;
        }
        ntf[t] = fmaxf(sqrtf(s), EPSV);
    } else if (t < 176) {
        int r = t - 112;
        float s = 0.f;
        for (int c2 = 0; c2 < 32; c2++) {
            u32 w = cpu32[r * 36 + c2];
            union { u32 i; float f; } x, y; x.i = w << 16; y.i = w & 0xFFFF0000u;
            s += x.f * x.f + y.f * y.f;
        }
        ncf[r] = fmaxf(sqrtf(s), EPSV);
    }
    for (int u = wid; u < 28; u += 8) {            // jt 0..6 x mt 0..3, K=64
        int jt = u >> 2, mt = u & 3;
        f4 acc = {0.f, 0.f, 0.f, 0.f};
        #pragma unroll
        for (int ks = 0; ks < 2; ks++) {
            bf8 a  = *(const bf8*)(tp16 + (jt * 16 + l15) * 72 + ks * 32 + quad * 8);
            bf8 bb = *(const bf8*)(cp16 + (mt * 16 + l15) * 72 + ks * 32 + quad * 8);
            acc = __builtin_amdgcn_mfma_f32_16x16x32_bf16(a, bb, acc, 0, 0, 0);
        }
        int m = mt * 16 + l15, j0 = jt * 16 + quad * 4;
        for (int r = 0; r < 4; r++) Wf[(j0 + r) * 68 + m] = acc[r];
    }
    __syncthreads();

    // ===== P2b: softmax rows -> attn (overwrites tp region) =====
    for (int j = wid; j < 112; j += 8) {
        float sc = -INFINITY;
        if (lane < NM && msk[lane] == 0)
            sc = Wf[j * 68 + lane] / (ntf[j] * ncf[lane]);
        float mx = sc;
        for (int o = 32; o; o >>= 1) mx = fmaxf(mx, __shfl_xor(mx, o, 64));
        float p = (mx > -INFINITY) ? __expf(sc - mx) : 0.f;
        float sm = p;
        for (int o = 32; o; o >>= 1) sm += __shfl_xor(sm, o, 64);
        float inv = (sm > 0.f) ? 1.f / sm : 0.f;
        at16[j * 72 + lane] = (lane < NM) ? f2bh(p * inv) : (u16)0;
    }
    __syncthreads();

    // ===== P3: bu = u @ Bc^T(global) + b -> W+0 row-major [m][e] =====
    for (int u = wid; u < 32; u += 8) {            // mt 0..3 x et 0..7, K=128
        int mt = u >> 3, et = u & 7;
        const float* brow = Bc_w + (size_t)(et * 16 + l15) * NE;
        float bv = bcb[et * 16 + l15];
        f4 acc = {bv, bv, bv, bv};
        #pragma unroll
        for (int ks = 0; ks < 4; ks++) {
            bf8 a  = *(const bf8*)(us16 + (mt * 16 + l15) * 136 + ks * 32 + quad * 8);
            bf8 bb = gfrag(brow + ks * 32 + quad * 8);
            acc = __builtin_amdgcn_mfma_f32_16x16x32_bf16(a, bb, acc, 0, 0, 0);
        }
        int e = et * 16 + l15, m0 = mt * 16 + quad * 4;
        for (int r = 0; r < 4; r++) buW[(m0 + r) * 136 + e] = f2bh(acc[r]);
    }
    __syncthreads();

    // ===== P4: gT = R(global) @ bu^T -> [e][m] stride 68 =====
    for (int u = wid; u < 32; u += 8) {            // et 0..7 x mt 0..3, K=128
        int et = u >> 2, mt = u & 3;
        const float* arow = R_w + (size_t)(et * 16 + l15) * NE;
        f4 acc = {0.f, 0.f, 0.f, 0.f};
        #pragma unroll
        for (int ks = 0; ks < 4; ks++) {
            bf8 a  = gfrag(arow + ks * 32 + quad * 8);
            bf8 bb = *(const bf8*)(buW + (mt * 16 + l15) * 136 + ks * 32 + quad * 8);
            acc = __builtin_amdgcn_mfma_f32_16x16x32_bf16(a, bb, acc, 0, 0, 0);
        }
        int m = mt * 16 + l15, e0 = et * 16 + quad * 4;
        for (int r = 0; r < 4; r++) gT16[(e0 + r) * 68 + m] = f2bh(acc[r]);
    }
    __syncthreads();

    // ===== P5: out = attn @ G + R_b -> global f32 =====
    for (int u = wid; u < 56; u += 8) {            // jt 0..6 x et 0..7, K=64
        int jt = u >> 3, et = u & 7;
        float bv = rb[et * 16 + l15];
        f4 acc = {bv, bv, bv, bv};
        #pragma unroll
        for (int ks = 0; ks < 2; ks++) {
            bf8 a  = *(const bf8*)(at16 + (jt * 16 + l15) * 72 + ks * 32 + quad * 8);
            bf8 bb = *(const bf8*)(gT16 + (et * 16 + l15) * 68 + ks * 32 + quad * 8);
            acc = __builtin_amdgcn_mfma_f32_16x16x32_bf16(a, bb, acc, 0, 0, 0);
        }
        int e = et * 16 + l15, j0 = jt * 16 + quad * 4;
        for (int r = 0; r < 4; r++) {
            int j = j0 + r;
            if (j < NJ) out[((size_t)b * NJ + j) * NE + e] = acc[r];
        }
    }
}

extern "C" void kernel_launch(void* const* d_in, const int* in_sizes, int n_in,
                              void* d_out, int out_size, void* d_ws, size_t ws_size,
                              hipStream_t stream) {
    const int*   titems  = (const int*)d_in[0];
    const int*   citems  = (const int*)d_in[1];
    const int*   pad_ids = (const int*)d_in[2];
    const float* t_emb   = (const float*)d_in[3];
    const float* c_emb   = (const float*)d_in[4];
    const float* Ac_w    = (const float*)d_in[5];
    const float* Ac_b    = (const float*)d_in[6];
    const float* At_w    = (const float*)d_in[7];
    const float* At_b    = (const float*)d_in[8];
    const float* Bc_w    = (const float*)d_in[9];
    const float* Bc_b    = (const float*)d_in[10];
    const float* R_w     = (const float*)d_in[11];
    const float* R_b     = (const float*)d_in[12];
    float* out = (float*)d_out;

    aitv_kernel<<<NB, NT, 0, stream>>>(titems, citems, pad_ids, t_emb, c_emb,
                                       Ac_w, Ac_b, At_w, At_b, Bc_w, Bc_b,
                                       R_w, R_b, out);
}

// Round 7
// 190.870 us; speedup vs baseline: 2.3677x; 1.0677x over previous
//
#include <hip/hip_runtime.h>

typedef unsigned short u16;
typedef unsigned int   u32;
typedef short bf8 __attribute__((ext_vector_type(8)));   // 8 bf16 payloads (4 VGPRs)
typedef float f4  __attribute__((ext_vector_type(4)));   // MFMA accumulator

#define NB   512
#define NJ   101
#define NM   50
#define NE   128
#define ND   60
#define NP   5120
#define NT   512
#define EPSV 1e-6f

// ---- LDS arena (byte offsets) ----
#define U_B    0         // u bf16 [64][136] = 17408
#define T_B    17408     // tp -> attn bf16 [112][72] = 16128
#define C_B    33536     // cp bf16 [64][72] = 9216
#define H_B    42752     // hT bf16 [128][72] = 18432  (hT[e][m] = h[m][e])
#define NT2_B  61184     // f32[112] sum tp^2
#define NC2_B  61632     // f32[64]  sum cp^2
#define BAT_B  61888     // f32[64]  At_b zero-padded
#define BAC_B  62144     // f32[64]  Ac_b zero-padded
#define RB2_B  62400     // f32[128] folded bias
#define MSK_B  62912     // int[64]
#define TIDX_B 63168     // int[112]
#define ARENA  63616

__device__ __forceinline__ u16 f2bh(float f) {
    return (u16)((__float_as_uint(f) + 0x8000u) >> 16);
}
__device__ __forceinline__ u32 pk2(float a, float b) {
    u32 ia = __float_as_uint(a) + 0x8000u;
    u32 ib = __float_as_uint(b) + 0x8000u;
    return (ia >> 16) | (ib & 0xFFFF0000u);
}
__device__ __forceinline__ bf8 gfrag(const float* p) {    // 8 f32 -> bf16 frag
    const float4* q = (const float4*)p;
    float4 x = q[0], y = q[1];
    union { u32 u[4]; bf8 v; } r;
    r.u[0] = pk2(x.x, x.y); r.u[1] = pk2(x.z, x.w);
    r.u[2] = pk2(y.x, y.y); r.u[3] = pk2(y.z, y.w);
    return r.v;
}

// ===== Kernel A: W2T[e][k] = (R@Bc)[e][k]; rb2[e] = Bc_b.R[e] + R_b[e] =====
__global__ __launch_bounds__(128) void w2_kernel(
    const float* __restrict__ Bc_w, const float* __restrict__ Bc_b,
    const float* __restrict__ R_w,  const float* __restrict__ R_b,
    u16* __restrict__ w2t, float* __restrict__ rb2)
{
    const int e = blockIdx.x, k = threadIdx.x;
    const float* Rrow = R_w + e * NE;
    float acc = 0.f;
    #pragma unroll 8
    for (int j = 0; j < NE; j++) acc += Rrow[j] * Bc_w[j * NE + k];   // coalesced over k
    w2t[e * NE + k] = f2bh(acc);
    float c = Bc_b[k] * Rrow[k];
    for (int o = 32; o; o >>= 1) c += __shfl_xor(c, o, 64);
    __shared__ float part[2];
    if ((k & 63) == 0) part[k >> 6] = c;
    __syncthreads();
    if (k == 0) rb2[e] = part[0] + part[1] + R_b[e];
}

// ===== Kernel B: per-batch fused attention =====
__global__ __launch_bounds__(NT, 4) void aitv_kernel(
    const int* __restrict__ titems, const int* __restrict__ citems,
    const int* __restrict__ pad_ids,
    const float* __restrict__ t_emb, const float* __restrict__ c_emb,
    const float* __restrict__ Ac_w,  const float* __restrict__ Ac_b,
    const float* __restrict__ At_w,  const float* __restrict__ At_b,
    const u16* __restrict__ w2t,     const float* __restrict__ rb2g,
    float* __restrict__ out)
{
    const int b    = blockIdx.x;
    const int t    = threadIdx.x;
    const int wid  = t >> 6;
    const int lane = t & 63;
    const int l15  = lane & 15;
    const int quad = lane >> 4;

    __shared__ __align__(16) char arena[ARENA];
    u16*   us16 = (u16*)(arena + U_B);   u32* us32 = (u32*)(arena + U_B);
    u16*   tp16 = (u16*)(arena + T_B);   u16* at16 = (u16*)(arena + T_B);
    u16*   cp16 = (u16*)(arena + C_B);
    u16*   hT16 = (u16*)(arena + H_B);
    float* nt2  = (float*)(arena + NT2_B);
    float* nc2  = (float*)(arena + NC2_B);
    float* bat  = (float*)(arena + BAT_B);
    float* bac  = (float*)(arena + BAC_B);
    float* rb2  = (float*)(arena + RB2_B);
    int*   msk  = (int*)(arena + MSK_B);
    int*   tidx = (int*)(arena + TIDX_B);

    // ===== P0: stage u bf16 (rows>=50 zero); indices; biases; zero accs =====
    for (int i = t; i < 64 * 64; i += NT) {
        int row = i >> 6, c2 = i & 63;
        u32 val = 0;
        if (row < NM) {
            int idx = citems[b * NM + row];              // wave-uniform
            float2 x = *(const float2*)(c_emb + (size_t)idx * NE + 2 * c2);
            val = pk2(x.x, x.y);
        }
        us32[row * 68 + c2] = val;
    }
    if (t < 112) { nt2[t] = 0.f; tidx[t] = titems[b * NJ + ((t < NJ) ? t : NJ - 1)]; }
    if (t >= 128 && t < 192) { int i = t - 128; nc2[i] = 0.f; msk[i] = 0; }
    if (t >= 192 && t < 256) {
        int i = t - 192;
        bat[i] = (i < ND) ? At_b[i] : 0.f;
        bac[i] = (i < ND) ? Ac_b[i] : 0.f;
    }
    if (t >= 256 && t < 384) rb2[t - 256] = rb2g[t - 256];
    __syncthreads();

    // ===== P1: pad-scan; tp, cp, hT MFMA units (76 units, mixed per wave) =====
    for (int i = t; i < NP; i += NT)
        if (pad_ids[i] == b) msk[pad_ids[NP + i]] = 1;

    for (int u = wid; u < 76; u += 8) {
        if (u < 28) {                       // tp[j][d] = v.At^T + b : jt 0..6, dt 0..3
            int jt = u >> 2, dt = u & 3;
            int d  = dt * 16 + l15;
            const float* vrow = t_emb + (size_t)tidx[jt * 16 + l15] * NE;
            const float* arow = At_w + (size_t)((d < ND) ? d : ND - 1) * NE;
            float bv = bat[d];
            f4 acc = {bv, bv, bv, bv};
            #pragma unroll
            for (int ks = 0; ks < 4; ks++) {
                bf8 a  = gfrag(vrow + ks * 32 + quad * 8);
                bf8 bb = gfrag(arow + ks * 32 + quad * 8);
                acc = __builtin_amdgcn_mfma_f32_16x16x32_bf16(a, bb, acc, 0, 0, 0);
            }
            int j0 = jt * 16 + quad * 4;
            #pragma unroll
            for (int r = 0; r < 4; r++) {
                float v = acc[r];
                tp16[(j0 + r) * 72 + d] = (d < ND) ? f2bh(v) : (u16)0;
                float q = (d < ND) ? v * v : 0.f;          // norm partial (f32, pre-round)
                q += __shfl_xor(q, 1, 64); q += __shfl_xor(q, 2, 64);
                q += __shfl_xor(q, 4, 64); q += __shfl_xor(q, 8, 64);
                if (l15 == 0) atomicAdd(&nt2[j0 + r], q);
            }
        } else if (u < 44) {                // cp[m][d] = u.Ac^T + b : mt 0..3, dt 0..3
            int uu = u - 28, mt = uu >> 2, dt = uu & 3;
            int d = dt * 16 + l15;
            const float* arow = Ac_w + (size_t)((d < ND) ? d : ND - 1) * NE;
            float bv = bac[d];
            f4 acc = {bv, bv, bv, bv};
            #pragma unroll
            for (int ks = 0; ks < 4; ks++) {
                bf8 a  = *(const bf8*)(us16 + (mt * 16 + l15) * 136 + ks * 32 + quad * 8);
                bf8 bb = gfrag(arow + ks * 32 + quad * 8);
                acc = __builtin_amdgcn_mfma_f32_16x16x32_bf16(a, bb, acc, 0, 0, 0);
            }
            int m0 = mt * 16 + quad * 4;
            #pragma unroll
            for (int r = 0; r < 4; r++) {
                float v = acc[r];
                cp16[(m0 + r) * 72 + d] = (d < ND) ? f2bh(v) : (u16)0;
                float q = (d < ND) ? v * v : 0.f;
                q += __shfl_xor(q, 1, 64); q += __shfl_xor(q, 2, 64);
                q += __shfl_xor(q, 4, 64); q += __shfl_xor(q, 8, 64);
                if (l15 == 0) atomicAdd(&nc2[m0 + r], q);
            }
        } else {                            // hT[e][m] = W2T.u^T : et 0..7, mt 0..3
            int uu = u - 44, et = uu >> 2, mt = uu & 3;
            const u16* arow = w2t + (size_t)(et * 16 + l15) * NE;   // global bf16
            f4 acc = {0.f, 0.f, 0.f, 0.f};
            #pragma unroll
            for (int ks = 0; ks < 4; ks++) {
                bf8 a  = *(const bf8*)(arow + ks * 32 + quad * 8);
                bf8 bb = *(const bf8*)(us16 + (mt * 16 + l15) * 136 + ks * 32 + quad * 8);
                acc = __builtin_amdgcn_mfma_f32_16x16x32_bf16(a, bb, acc, 0, 0, 0);
            }
            int e0 = et * 16 + quad * 4;
            for (int r = 0; r < 4; r++)
                hT16[(e0 + r) * 72 + mt * 16 + l15] = f2bh(acc[r]);
        }
    }
    __syncthreads();

    // ===== P2: scores (wave jt owns its 4 tiles) + in-register softmax -> attn =====
    if (wid < 7) {
        const int jt = wid;
        f4 S[4];
        #pragma unroll
        for (int mt = 0; mt < 4; mt++) {
            f4 acc = {0.f, 0.f, 0.f, 0.f};
            #pragma unroll
            for (int ks = 0; ks < 2; ks++) {
                bf8 a  = *(const bf8*)(tp16 + (jt * 16 + l15) * 72 + ks * 32 + quad * 8);
                bf8 bb = *(const bf8*)(cp16 + (mt * 16 + l15) * 72 + ks * 32 + quad * 8);
                acc = __builtin_amdgcn_mfma_f32_16x16x32_bf16(a, bb, acc, 0, 0, 0);
            }
            S[mt] = acc;
        }
        bool  valid[4]; float ncS[4];
        #pragma unroll
        for (int mt = 0; mt < 4; mt++) {
            int m = mt * 16 + l15;
            valid[mt] = (m < NM) && (msk[m] == 0);
            ncS[mt]   = valid[mt] ? fmaxf(sqrtf(nc2[m]), EPSV) : 1.f;
        }
        #pragma unroll
        for (int r = 0; r < 4; r++) {
            int j = jt * 16 + quad * 4 + r;
            float ntj = fmaxf(sqrtf(nt2[j]), EPSV);
            float x[4], mx = -INFINITY;
            #pragma unroll
            for (int mt = 0; mt < 4; mt++) {
                x[mt] = valid[mt] ? S[mt][r] / (ntj * ncS[mt]) : -INFINITY;
                mx = fmaxf(mx, x[mt]);
            }
            mx = fmaxf(mx, __shfl_xor(mx, 1, 64)); mx = fmaxf(mx, __shfl_xor(mx, 2, 64));
            mx = fmaxf(mx, __shfl_xor(mx, 4, 64)); mx = fmaxf(mx, __shfl_xor(mx, 8, 64));
            float p[4], sm = 0.f;
            #pragma unroll
            for (int mt = 0; mt < 4; mt++) {
                p[mt] = valid[mt] ? __expf(x[mt] - mx) : 0.f;
                sm += p[mt];
            }
            sm += __shfl_xor(sm, 1, 64); sm += __shfl_xor(sm, 2, 64);
            sm += __shfl_xor(sm, 4, 64); sm += __shfl_xor(sm, 8, 64);
            float inv = (sm > 0.f) ? 1.f / sm : 0.f;
            #pragma unroll
            for (int mt = 0; mt < 4; mt++)
                at16[j * 72 + mt * 16 + l15] = f2bh(p[mt] * inv);   // overwrites tp
        }
    }
    __syncthreads();

    // ===== P3: out = attn @ hT^T + rb2 -> global f32 =====
    for (int u = wid; u < 56; u += 8) {     // jt 0..6 x et 0..7, K=64
        int jt = u >> 3, et = u & 7;
        float bv = rb2[et * 16 + l15];
        f4 acc = {bv, bv, bv, bv};
        #pragma unroll
        for (int ks = 0; ks < 2; ks++) {
            bf8 a  = *(const bf8*)(at16 + (jt * 16 + l15) * 72 + ks * 32 + quad * 8);
            bf8 bb = *(const bf8*)(hT16 + (et * 16 + l15) * 72 + ks * 32 + quad * 8);
            acc = __builtin_amdgcn_mfma_f32_16x16x32_bf16(a, bb, acc, 0, 0, 0);
        }
        int e = et * 16 + l15, j0 = jt * 16 + quad * 4;
        for (int r = 0; r < 4; r++) {
            int j = j0 + r;
            if (j < NJ) out[((size_t)b * NJ + j) * NE + e] = acc[r];
        }
    }
}

extern "C" void kernel_launch(void* const* d_in, const int* in_sizes, int n_in,
                              void* d_out, int out_size, void* d_ws, size_t ws_size,
                              hipStream_t stream) {
    const int*   titems  = (const int*)d_in[0];
    const int*   citems  = (const int*)d_in[1];
    const int*   pad_ids = (const int*)d_in[2];
    const float* t_emb   = (const float*)d_in[3];
    const float* c_emb   = (const float*)d_in[4];
    const float* Ac_w    = (const float*)d_in[5];
    const float* Ac_b    = (const float*)d_in[6];
    const float* At_w    = (const float*)d_in[7];
    const float* At_b    = (const float*)d_in[8];
    const float* Bc_w    = (const float*)d_in[9];
    const float* Bc_b    = (const float*)d_in[10];
    const float* R_w     = (const float*)d_in[11];
    const float* R_b     = (const float*)d_in[12];
    float* out = (float*)d_out;

    u16*   w2t = (u16*)d_ws;                              // [128][128] bf16 = 32768B
    float* rb2 = (float*)((char*)d_ws + 32768);           // [128] f32

    w2_kernel<<<NE, NE, 0, stream>>>(Bc_w, Bc_b, R_w, R_b, w2t, rb2);
    aitv_kernel<<<NB, NT, 0, stream>>>(titems, citems, pad_ids, t_emb, c_emb,
                                       Ac_w, Ac_b, At_w, At_b, w2t, rb2, out);
}

// Round 8
// 184.715 us; speedup vs baseline: 2.4466x; 1.0333x over previous
//
#include <hip/hip_runtime.h>

typedef unsigned short u16;
typedef unsigned int   u32;
typedef short bf8 __attribute__((ext_vector_type(8)));   // 8 bf16 payloads (4 VGPRs)
typedef float f4  __attribute__((ext_vector_type(4)));   // MFMA accumulator

#define NB   512
#define NJ   101
#define NM   50
#define NE   128
#define ND   60
#define NP   5120
#define NT   512
#define EPSV 1e-6f

// ---- LDS arena (byte offsets) ----
#define T_B    0         // tp -> attn bf16 [112][72] = 16128
#define C_B    16128     // cp bf16 [64][72] = 9216
#define H_B    25344     // hT bf16 [128][72] = 18432  (hT[e][m])
#define NT2_B  43776     // f32[112] sum tp^2
#define NC2_B  44224     // f32[64]  sum cp^2
#define MSK_B  44480     // int[64]
#define ARENA  44736

__device__ __forceinline__ u16 f2bh(float f) {
    return (u16)((__float_as_uint(f) + 0x8000u) >> 16);
}
__device__ __forceinline__ u32 pk2(float a, float b) {
    u32 ia = __float_as_uint(a) + 0x8000u;
    u32 ib = __float_as_uint(b) + 0x8000u;
    return (ia >> 16) | (ib & 0xFFFF0000u);
}
__device__ __forceinline__ bf8 gfrag(const float* p) {    // 8 f32 -> bf16 frag
    const float4* q = (const float4*)p;
    float4 x = q[0], y = q[1];
    union { u32 u[4]; bf8 v; } r;
    r.u[0] = pk2(x.x, x.y); r.u[1] = pk2(x.z, x.w);
    r.u[2] = pk2(y.x, y.y); r.u[3] = pk2(y.z, y.w);
    return r.v;
}

// ===== Kernel A: W2T[e][k] = (R@Bc)[e][k]; rb2[e] = Bc_b.R[e] + R_b[e] =====
__global__ __launch_bounds__(128) void w2_kernel(
    const float* __restrict__ Bc_w, const float* __restrict__ Bc_b,
    const float* __restrict__ R_w,  const float* __restrict__ R_b,
    u16* __restrict__ w2t, float* __restrict__ rb2)
{
    const int e = blockIdx.x, k = threadIdx.x;
    const float* Rrow = R_w + e * NE;
    float a0 = 0.f, a1 = 0.f, a2 = 0.f, a3 = 0.f;   // 4 independent chains
    #pragma unroll 8
    for (int j = 0; j < NE; j += 4) {
        a0 += Rrow[j]     * Bc_w[j * NE + k];
        a1 += Rrow[j + 1] * Bc_w[(j + 1) * NE + k];
        a2 += Rrow[j + 2] * Bc_w[(j + 2) * NE + k];
        a3 += Rrow[j + 3] * Bc_w[(j + 3) * NE + k];
    }
    w2t[e * NE + k] = f2bh((a0 + a1) + (a2 + a3));
    float c = Bc_b[k] * Rrow[k];
    for (int o = 32; o; o >>= 1) c += __shfl_xor(c, o, 64);
    __shared__ float part[2];
    if ((k & 63) == 0) part[k >> 6] = c;
    __syncthreads();
    if (k == 0) rb2[e] = part[0] + part[1] + R_b[e];
}

// ===== Kernel B: per-batch fused attention =====
__global__ __launch_bounds__(NT, 4) void aitv_kernel(
    const int* __restrict__ titems, const int* __restrict__ citems,
    const int* __restrict__ pad_ids,
    const float* __restrict__ t_emb, const float* __restrict__ c_emb,
    const float* __restrict__ Ac_w,  const float* __restrict__ Ac_b,
    const float* __restrict__ At_w,  const float* __restrict__ At_b,
    const u16* __restrict__ w2t,     const float* __restrict__ rb2g,
    float* __restrict__ out)
{
    const int b    = blockIdx.x;
    const int t    = threadIdx.x;
    const int wid  = t >> 6;
    const int lane = t & 63;
    const int l15  = lane & 15;
    const int quad = lane >> 4;

    __shared__ __align__(16) char arena[ARENA];
    u16*   tp16 = (u16*)(arena + T_B);   u16* at16 = (u16*)(arena + T_B);
    u16*   cp16 = (u16*)(arena + C_B);
    u16*   hT16 = (u16*)(arena + H_B);
    float* nt2  = (float*)(arena + NT2_B);
    float* nc2  = (float*)(arena + NC2_B);
    int*   msk  = (int*)(arena + MSK_B);

    // ===== P0: zero accumulators + mask (no staging) =====
    if (t < 112) nt2[t] = 0.f;
    else if (t < 176) nc2[t - 112] = 0.f;
    else if (t < 240) msk[t - 176] = 0;
    __syncthreads();

    // ===== P1: pad scan; 15 work groups with frag-register reuse =====
    for (int i = t; i < NP; i += NT)
        if (pad_ids[i] == b) msk[pad_ids[NP + i]] = 1;

    for (int g = wid; g < 15; g += 8) {
        if (g < 7) {
            // --- tp group: jt = g. Load v A-frags ONCE, loop dt over At. ---
            const int jt = g;
            const int j  = jt * 16 + l15;
            const float* vrow = t_emb + (size_t)titems[b * NJ + ((j < NJ) ? j : NJ - 1)] * NE;
            bf8 A[4];
            #pragma unroll
            for (int ks = 0; ks < 4; ks++) A[ks] = gfrag(vrow + ks * 32 + quad * 8);
            #pragma unroll
            for (int dt = 0; dt < 4; dt++) {
                const int d = dt * 16 + l15;
                const float* arow = At_w + (size_t)((d < ND) ? d : 0) * NE;
                float bv = (d < ND) ? At_b[d] : 0.f;
                f4 acc = {bv, bv, bv, bv};
                #pragma unroll
                for (int ks = 0; ks < 4; ks++)
                    acc = __builtin_amdgcn_mfma_f32_16x16x32_bf16(
                        A[ks], gfrag(arow + ks * 32 + quad * 8), acc, 0, 0, 0);
                const int j0 = jt * 16 + quad * 4;
                #pragma unroll
                for (int r = 0; r < 4; r++) {
                    float v = acc[r];
                    tp16[(j0 + r) * 72 + d] = (d < ND) ? f2bh(v) : (u16)0;
                    float q = (d < ND) ? v * v : 0.f;
                    q += __shfl_xor(q, 1, 64); q += __shfl_xor(q, 2, 64);
                    q += __shfl_xor(q, 4, 64); q += __shfl_xor(q, 8, 64);
                    if (l15 == 0) atomicAdd(&nt2[j0 + r], q);
                }
            }
        } else if (g < 11) {
            // --- u group A: mt = g-7. Load u-frag ONCE: A for cp (4 dt), B for hT (et 0..3). ---
            const int mt = g - 7;
            const int m  = mt * 16 + l15;
            const float* urow = c_emb + (size_t)citems[b * NM + ((m < NM) ? m : 0)] * NE;
            bf8 U[4];
            #pragma unroll
            for (int ks = 0; ks < 4; ks++) U[ks] = gfrag(urow + ks * 32 + quad * 8);
            #pragma unroll
            for (int dt = 0; dt < 4; dt++) {
                const int d = dt * 16 + l15;
                const float* arow = Ac_w + (size_t)((d < ND) ? d : 0) * NE;
                float bv = (d < ND) ? Ac_b[d] : 0.f;
                f4 acc = {bv, bv, bv, bv};
                #pragma unroll
                for (int ks = 0; ks < 4; ks++)
                    acc = __builtin_amdgcn_mfma_f32_16x16x32_bf16(
                        U[ks], gfrag(arow + ks * 32 + quad * 8), acc, 0, 0, 0);
                const int m0 = mt * 16 + quad * 4;
                #pragma unroll
                for (int r = 0; r < 4; r++) {
                    float v = acc[r];
                    cp16[(m0 + r) * 72 + d] = (d < ND) ? f2bh(v) : (u16)0;
                    float q = (d < ND) ? v * v : 0.f;
                    q += __shfl_xor(q, 1, 64); q += __shfl_xor(q, 2, 64);
                    q += __shfl_xor(q, 4, 64); q += __shfl_xor(q, 8, 64);
                    if (l15 == 0) atomicAdd(&nc2[m0 + r], q);
                }
            }
            #pragma unroll
            for (int et = 0; et < 4; et++) {
                const u16* wrow = w2t + (size_t)(et * 16 + l15) * NE;
                f4 acc = {0.f, 0.f, 0.f, 0.f};
                #pragma unroll
                for (int ks = 0; ks < 4; ks++)
                    acc = __builtin_amdgcn_mfma_f32_16x16x32_bf16(
                        *(const bf8*)(wrow + ks * 32 + quad * 8), U[ks], acc, 0, 0, 0);
                const int e0 = et * 16 + quad * 4;
                for (int r = 0; r < 4; r++)
                    hT16[(e0 + r) * 72 + mt * 16 + l15] = f2bh(acc[r]);
            }
        } else {
            // --- u group B: mt = g-11. Reload u-frag, hT et 4..7. ---
            const int mt = g - 11;
            const int m  = mt * 16 + l15;
            const float* urow = c_emb + (size_t)citems[b * NM + ((m < NM) ? m : 0)] * NE;
            bf8 U[4];
            #pragma unroll
            for (int ks = 0; ks < 4; ks++) U[ks] = gfrag(urow + ks * 32 + quad * 8);
            #pragma unroll
            for (int et = 4; et < 8; et++) {
                const u16* wrow = w2t + (size_t)(et * 16 + l15) * NE;
                f4 acc = {0.f, 0.f, 0.f, 0.f};
                #pragma unroll
                for (int ks = 0; ks < 4; ks++)
                    acc = __builtin_amdgcn_mfma_f32_16x16x32_bf16(
                        *(const bf8*)(wrow + ks * 32 + quad * 8), U[ks], acc, 0, 0, 0);
                const int e0 = et * 16 + quad * 4;
                for (int r = 0; r < 4; r++)
                    hT16[(e0 + r) * 72 + mt * 16 + l15] = f2bh(acc[r]);
            }
        }
    }
    __syncthreads();

    // ===== P2: scores + in-register softmax -> attn (overwrites tp) =====
    if (wid < 7) {
        const int jt = wid;
        f4 S[4];
        #pragma unroll
        for (int mt = 0; mt < 4; mt++) {
            f4 acc = {0.f, 0.f, 0.f, 0.f};
            #pragma unroll
            for (int ks = 0; ks < 2; ks++) {
                bf8 a  = *(const bf8*)(tp16 + (jt * 16 + l15) * 72 + ks * 32 + quad * 8);
                bf8 bb = *(const bf8*)(cp16 + (mt * 16 + l15) * 72 + ks * 32 + quad * 8);
                acc = __builtin_amdgcn_mfma_f32_16x16x32_bf16(a, bb, acc, 0, 0, 0);
            }
            S[mt] = acc;
        }
        bool valid[4]; float ncS[4];
        #pragma unroll
        for (int mt = 0; mt < 4; mt++) {
            int m = mt * 16 + l15;
            valid[mt] = (m < NM) && (msk[m] == 0);
            ncS[mt]   = valid[mt] ? fmaxf(sqrtf(nc2[m]), EPSV) : 1.f;
        }
        #pragma unroll
        for (int r = 0; r < 4; r++) {
            int j = jt * 16 + quad * 4 + r;
            float ntj = fmaxf(sqrtf(nt2[j]), EPSV);
            float x[4], mx = -INFINITY;
            #pragma unroll
            for (int mt = 0; mt < 4; mt++) {
                x[mt] = valid[mt] ? S[mt][r] / (ntj * ncS[mt]) : -INFINITY;
                mx = fmaxf(mx, x[mt]);
            }
            mx = fmaxf(mx, __shfl_xor(mx, 1, 64)); mx = fmaxf(mx, __shfl_xor(mx, 2, 64));
            mx = fmaxf(mx, __shfl_xor(mx, 4, 64)); mx = fmaxf(mx, __shfl_xor(mx, 8, 64));
            float p[4], sm = 0.f;
            #pragma unroll
            for (int mt = 0; mt < 4; mt++) {
                p[mt] = valid[mt] ? __expf(x[mt] - mx) : 0.f;
                sm += p[mt];
            }
            sm += __shfl_xor(sm, 1, 64); sm += __shfl_xor(sm, 2, 64);
            sm += __shfl_xor(sm, 4, 64); sm += __shfl_xor(sm, 8, 64);
            float inv = (sm > 0.f) ? 1.f / sm : 0.f;
            #pragma unroll
            for (int mt = 0; mt < 4; mt++)
                at16[j * 72 + mt * 16 + l15] = f2bh(p[mt] * inv);
        }
    }
    __syncthreads();

    // ===== P3: out = attn @ hT^T + rb2 -> global f32 =====
    for (int u = wid; u < 56; u += 8) {     // jt 0..6 x et 0..7, K=64
        int jt = u >> 3, et = u & 7;
        float bv = rb2g[et * 16 + l15];
        f4 acc = {bv, bv, bv, bv};
        #pragma unroll
        for (int ks = 0; ks < 2; ks++) {
            bf8 a  = *(const bf8*)(at16 + (jt * 16 + l15) * 72 + ks * 32 + quad * 8);
            bf8 bb = *(const bf8*)(hT16 + (et * 16 + l15) * 72 + ks * 32 + quad * 8);
            acc = __builtin_amdgcn_mfma_f32_16x16x32_bf16(a, bb, acc, 0, 0, 0);
        }
        int e = et * 16 + l15, j0 = jt * 16 + quad * 4;
        for (int r = 0; r < 4; r++) {
            int j = j0 + r;
            if (j < NJ) out[((size_t)b * NJ + j) * NE + e] = acc[r];
        }
    }
}

extern "C" void kernel_launch(void* const* d_in, const int* in_sizes, int n_in,
                              void* d_out, int out_size, void* d_ws, size_t ws_size,
                              hipStream_t stream) {
    const int*   titems  = (const int*)d_in[0];
    const int*   citems  = (const int*)d_in[1];
    const int*   pad_ids = (const int*)d_in[2];
    const float* t_emb   = (const float*)d_in[3];
    const float* c_emb   = (const float*)d_in[4];
    const float* Ac_w    = (const float*)d_in[5];
    const float* Ac_b    = (const float*)d_in[6];
    const float* At_w    = (const float*)d_in[7];
    const float* At_b    = (const float*)d_in[8];
    const float* Bc_w    = (const float*)d_in[9];
    const float* Bc_b    = (const float*)d_in[10];
    const float* R_w     = (const float*)d_in[11];
    const float* R_b     = (const float*)d_in[12];
    float* out = (float*)d_out;

    u16*   w2t = (u16*)d_ws;                              // [128][128] bf16 = 32768B
    float* rb2 = (float*)((char*)d_ws + 32768);           // [128] f32

    w2_kernel<<<NE, NE, 0, stream>>>(Bc_w, Bc_b, R_w, R_b, w2t, rb2);
    aitv_kernel<<<NB, NT, 0, stream>>>(titems, citems, pad_ids, t_emb, c_emb,
                                       Ac_w, Ac_b, At_w, At_b, w2t, rb2, out);
}

// Round 9
// 182.552 us; speedup vs baseline: 2.4756x; 1.0118x over previous
//
#include <hip/hip_runtime.h>

typedef unsigned short u16;
typedef unsigned int   u32;
typedef short bf8 __attribute__((ext_vector_type(8)));   // 8 bf16 payloads (4 VGPRs)
typedef float f4  __attribute__((ext_vector_type(4)));   // MFMA accumulator

#define NB   512
#define NJ   101
#define NM   50
#define NE   128
#define ND   60
#define NP   5120
#define NT   512
#define EPSV 1e-6f

// ---- LDS arena (byte offsets) ----
#define U_B    0         // u bf16 [64][136] = 17408  (staged coalesced, zero-padded)
#define T_B    17408     // tp -> attn bf16 [112][72] = 16128
#define C_B    33536     // cp bf16 [64][72] = 9216
#define H_B    42752     // hT bf16 [128][72] = 18432  (hT[e][m])
#define NT2_B  61184     // f32[112] sum tp^2
#define NC2_B  61632     // f32[64]  sum cp^2
#define MSK_B  61888     // int[64]
#define ARENA  62144

__device__ __forceinline__ u16 f2bh(float f) {
    return (u16)((__float_as_uint(f) + 0x8000u) >> 16);
}
__device__ __forceinline__ u32 pk2(float a, float b) {
    u32 ia = __float_as_uint(a) + 0x8000u;
    u32 ib = __float_as_uint(b) + 0x8000u;
    return (ia >> 16) | (ib & 0xFFFF0000u);
}
__device__ __forceinline__ bf8 gfrag(const float* p) {    // 8 f32 -> bf16 frag
    const float4* q = (const float4*)p;
    float4 x = q[0], y = q[1];
    union { u32 u[4]; bf8 v; } r;
    r.u[0] = pk2(x.x, x.y); r.u[1] = pk2(x.z, x.w);
    r.u[2] = pk2(y.x, y.y); r.u[3] = pk2(y.z, y.w);
    return r.v;
}

// ===== Kernel A: W2T[e][k] = (R@Bc)[e][k]; rb2[e] = Bc_b.R[e] + R_b[e] =====
__global__ __launch_bounds__(128) void w2_kernel(
    const float* __restrict__ Bc_w, const float* __restrict__ Bc_b,
    const float* __restrict__ R_w,  const float* __restrict__ R_b,
    u16* __restrict__ w2t, float* __restrict__ rb2)
{
    const int e = blockIdx.x, k = threadIdx.x;
    const float* Rrow = R_w + e * NE;
    float a0 = 0.f, a1 = 0.f, a2 = 0.f, a3 = 0.f;   // 4 independent chains
    #pragma unroll 8
    for (int j = 0; j < NE; j += 4) {
        a0 += Rrow[j]     * Bc_w[j * NE + k];
        a1 += Rrow[j + 1] * Bc_w[(j + 1) * NE + k];
        a2 += Rrow[j + 2] * Bc_w[(j + 2) * NE + k];
        a3 += Rrow[j + 3] * Bc_w[(j + 3) * NE + k];
    }
    w2t[e * NE + k] = f2bh((a0 + a1) + (a2 + a3));
    float c = Bc_b[k] * Rrow[k];
    for (int o = 32; o; o >>= 1) c += __shfl_xor(c, o, 64);
    __shared__ float part[2];
    if ((k & 63) == 0) part[k >> 6] = c;
    __syncthreads();
    if (k == 0) rb2[e] = part[0] + part[1] + R_b[e];
}

// ===== Kernel B: per-batch fused attention =====
__global__ __launch_bounds__(NT, 4) void aitv_kernel(
    const int* __restrict__ titems, const int* __restrict__ citems,
    const int* __restrict__ pad_ids,
    const float* __restrict__ t_emb, const float* __restrict__ c_emb,
    const float* __restrict__ Ac_w,  const float* __restrict__ Ac_b,
    const float* __restrict__ At_w,  const float* __restrict__ At_b,
    const u16* __restrict__ w2t,     const float* __restrict__ rb2g,
    float* __restrict__ out)
{
    const int b    = blockIdx.x;
    const int t    = threadIdx.x;
    const int wid  = t >> 6;
    const int lane = t & 63;
    const int l15  = lane & 15;
    const int quad = lane >> 4;

    __shared__ __align__(16) char arena[ARENA];
    u16*   us16 = (u16*)(arena + U_B);   u32* us32 = (u32*)(arena + U_B);
    u16*   tp16 = (u16*)(arena + T_B);   u16* at16 = (u16*)(arena + T_B);
    u16*   cp16 = (u16*)(arena + C_B);
    u16*   hT16 = (u16*)(arena + H_B);
    float* nt2  = (float*)(arena + NT2_B);
    float* nc2  = (float*)(arena + NC2_B);
    int*   msk  = (int*)(arena + MSK_B);

    // ===== P0: stage u coalesced (bf16, rows>=50 zero); zero accs + mask =====
    for (int i = t; i < 64 * 64; i += NT) {        // 8 independent loads/thread
        int row = i >> 6, c2 = i & 63;             // row wave-uniform -> coalesced burst
        u32 val = 0;
        if (row < NM) {
            int idx = citems[b * NM + row];
            float2 x = *(const float2*)(c_emb + (size_t)idx * NE + 2 * c2);
            val = pk2(x.x, x.y);
        }
        us32[row * 68 + c2] = val;
    }
    if (t < 112) nt2[t] = 0.f;
    else if (t < 176) nc2[t - 112] = 0.f;
    else if (t < 240) msk[t - 176] = 0;
    __syncthreads();

    // ===== P1: pad scan; 11 light groups (7 tp + 4 cp) =====
    for (int i = t; i < NP; i += NT)
        if (pad_ids[i] == b) msk[pad_ids[NP + i]] = 1;

    for (int g = wid; g < 11; g += 8) {
        if (g < 7) {
            // --- tp group: jt = g. Load v A-frags ONCE (scattered gather), loop dt. ---
            const int jt = g;
            const int j  = jt * 16 + l15;
            const float* vrow = t_emb + (size_t)titems[b * NJ + ((j < NJ) ? j : NJ - 1)] * NE;
            bf8 A[4];
            #pragma unroll
            for (int ks = 0; ks < 4; ks++) A[ks] = gfrag(vrow + ks * 32 + quad * 8);
            #pragma unroll
            for (int dt = 0; dt < 4; dt++) {
                const int d = dt * 16 + l15;
                const float* arow = At_w + (size_t)((d < ND) ? d : 0) * NE;
                float bv = (d < ND) ? At_b[d] : 0.f;
                f4 acc = {bv, bv, bv, bv};
                #pragma unroll
                for (int ks = 0; ks < 4; ks++)
                    acc = __builtin_amdgcn_mfma_f32_16x16x32_bf16(
                        A[ks], gfrag(arow + ks * 32 + quad * 8), acc, 0, 0, 0);
                const int j0 = jt * 16 + quad * 4;
                #pragma unroll
                for (int r = 0; r < 4; r++) {
                    float v = acc[r];
                    tp16[(j0 + r) * 72 + d] = (d < ND) ? f2bh(v) : (u16)0;
                    float q = (d < ND) ? v * v : 0.f;
                    q += __shfl_xor(q, 1, 64); q += __shfl_xor(q, 2, 64);
                    q += __shfl_xor(q, 4, 64); q += __shfl_xor(q, 8, 64);
                    if (l15 == 0) atomicAdd(&nt2[j0 + r], q);
                }
            }
        } else {
            // --- cp group: mt = g-7. u-frags from LDS; weights from global L2. ---
            const int mt = g - 7;
            bf8 U[4];
            #pragma unroll
            for (int ks = 0; ks < 4; ks++)
                U[ks] = *(const bf8*)(us16 + (mt * 16 + l15) * 136 + ks * 32 + quad * 8);
            #pragma unroll
            for (int dt = 0; dt < 4; dt++) {
                const int d = dt * 16 + l15;
                const float* arow = Ac_w + (size_t)((d < ND) ? d : 0) * NE;
                float bv = (d < ND) ? Ac_b[d] : 0.f;
                f4 acc = {bv, bv, bv, bv};
                #pragma unroll
                for (int ks = 0; ks < 4; ks++)
                    acc = __builtin_amdgcn_mfma_f32_16x16x32_bf16(
                        U[ks], gfrag(arow + ks * 32 + quad * 8), acc, 0, 0, 0);
                const int m0 = mt * 16 + quad * 4;
                #pragma unroll
                for (int r = 0; r < 4; r++) {
                    float v = acc[r];
                    cp16[(m0 + r) * 72 + d] = (d < ND) ? f2bh(v) : (u16)0;
                    float q = (d < ND) ? v * v : 0.f;
                    q += __shfl_xor(q, 1, 64); q += __shfl_xor(q, 2, 64);
                    q += __shfl_xor(q, 4, 64); q += __shfl_xor(q, 8, 64);
                    if (l15 == 0) atomicAdd(&nc2[m0 + r], q);
                }
            }
        }
    }
    __syncthreads();

    // ===== P2: hT units on all 8 waves + scores/softmax on waves 0..6 =====
    for (int u = wid; u < 32; u += 8) {            // hT[e][m] = W2T.u^T
        int et = u >> 2, mt = u & 3;
        const u16* wrow = w2t + (size_t)(et * 16 + l15) * NE;
        bf8 U[4];
        #pragma unroll
        for (int ks = 0; ks < 4; ks++)
            U[ks] = *(const bf8*)(us16 + (mt * 16 + l15) * 136 + ks * 32 + quad * 8);
        f4 acc = {0.f, 0.f, 0.f, 0.f};
        #pragma unroll
        for (int ks = 0; ks < 4; ks++)
            acc = __builtin_amdgcn_mfma_f32_16x16x32_bf16(
                *(const bf8*)(wrow + ks * 32 + quad * 8), U[ks], acc, 0, 0, 0);
        const int e0 = et * 16 + quad * 4;
        for (int r = 0; r < 4; r++)
            hT16[(e0 + r) * 72 + mt * 16 + l15] = f2bh(acc[r]);
    }
    if (wid < 7) {
        const int jt = wid;
        f4 S[4];
        #pragma unroll
        for (int mt = 0; mt < 4; mt++) {
            f4 acc = {0.f, 0.f, 0.f, 0.f};
            #pragma unroll
            for (int ks = 0; ks < 2; ks++) {
                bf8 a  = *(const bf8*)(tp16 + (jt * 16 + l15) * 72 + ks * 32 + quad * 8);
                bf8 bb = *(const bf8*)(cp16 + (mt * 16 + l15) * 72 + ks * 32 + quad * 8);
                acc = __builtin_amdgcn_mfma_f32_16x16x32_bf16(a, bb, acc, 0, 0, 0);
            }
            S[mt] = acc;
        }
        bool valid[4]; float ncS[4];
        #pragma unroll
        for (int mt = 0; mt < 4; mt++) {
            int m = mt * 16 + l15;
            valid[mt] = (m < NM) && (msk[m] == 0);
            ncS[mt]   = valid[mt] ? fmaxf(sqrtf(nc2[m]), EPSV) : 1.f;
        }
        #pragma unroll
        for (int r = 0; r < 4; r++) {
            int j = jt * 16 + quad * 4 + r;
            float ntj = fmaxf(sqrtf(nt2[j]), EPSV);
            float x[4], mx = -INFINITY;
            #pragma unroll
            for (int mt = 0; mt < 4; mt++) {
                x[mt] = valid[mt] ? S[mt][r] / (ntj * ncS[mt]) : -INFINITY;
                mx = fmaxf(mx, x[mt]);
            }
            mx = fmaxf(mx, __shfl_xor(mx, 1, 64)); mx = fmaxf(mx, __shfl_xor(mx, 2, 64));
            mx = fmaxf(mx, __shfl_xor(mx, 4, 64)); mx = fmaxf(mx, __shfl_xor(mx, 8, 64));
            float p[4], sm = 0.f;
            #pragma unroll
            for (int mt = 0; mt < 4; mt++) {
                p[mt] = valid[mt] ? __expf(x[mt] - mx) : 0.f;
                sm += p[mt];
            }
            sm += __shfl_xor(sm, 1, 64); sm += __shfl_xor(sm, 2, 64);
            sm += __shfl_xor(sm, 4, 64); sm += __shfl_xor(sm, 8, 64);
            float inv = (sm > 0.f) ? 1.f / sm : 0.f;
            #pragma unroll
            for (int mt = 0; mt < 4; mt++)
                at16[j * 72 + mt * 16 + l15] = f2bh(p[mt] * inv);
        }
    }
    __syncthreads();

    // ===== P3: out = attn @ hT^T + rb2 -> global f32 =====
    for (int u = wid; u < 56; u += 8) {            // jt 0..6 x et 0..7, K=64
        int jt = u >> 3, et = u & 7;
        float bv = rb2g[et * 16 + l15];
        f4 acc = {bv, bv, bv, bv};
        #pragma unroll
        for (int ks = 0; ks < 2; ks++) {
            bf8 a  = *(const bf8*)(at16 + (jt * 16 + l15) * 72 + ks * 32 + quad * 8);
            bf8 bb = *(const bf8*)(hT16 + (et * 16 + l15) * 72 + ks * 32 + quad * 8);
            acc = __builtin_amdgcn_mfma_f32_16x16x32_bf16(a, bb, acc, 0, 0, 0);
        }
        int e = et * 16 + l15, j0 = jt * 16 + quad * 4;
        for (int r = 0; r < 4; r++) {
            int j = j0 + r;
            if (j < NJ) out[((size_t)b * NJ + j) * NE + e] = acc[r];
        }
    }
}

extern "C" void kernel_launch(void* const* d_in, const int* in_sizes, int n_in,
                              void* d_out, int out_size, void* d_ws, size_t ws_size,
                              hipStream_t stream) {
    const int*   titems  = (const int*)d_in[0];
    const int*   citems  = (const int*)d_in[1];
    const int*   pad_ids = (const int*)d_in[2];
    const float* t_emb   = (const float*)d_in[3];
    const float* c_emb   = (const float*)d_in[4];
    const float* Ac_w    = (const float*)d_in[5];
    const float* Ac_b    = (const float*)d_in[6];
    const float* At_w    = (const float*)d_in[7];
    const float* At_b    = (const float*)d_in[8];
    const float* Bc_w    = (const float*)d_in[9];
    const float* Bc_b    = (const float*)d_in[10];
    const float* R_w     = (const float*)d_in[11];
    const float* R_b     = (const float*)d_in[12];
    float* out = (float*)d_out;

    u16*   w2t = (u16*)d_ws;                              // [128][128] bf16 = 32768B
    float* rb2 = (float*)((char*)d_ws + 32768);           // [128] f32

    w2_kernel<<<NE, NE, 0, stream>>>(Bc_w, Bc_b, R_w, R_b, w2t, rb2);
    aitv_kernel<<<NB, NT, 0, stream>>>(titems, citems, pad_ids, t_emb, c_emb,
                                       Ac_w, Ac_b, At_w, At_b, w2t, rb2, out);
}